// Round 8
// baseline (1165.367 us; speedup 1.0000x reference)
//
#include <hip/hip_runtime.h>

#define BB 256
#define TT 512
#define NN 128
#define GO_IDX 1
#define EOS_IDX 2
#define TSPLIT 496            // bp rows t in [1,TSPLIT) in LDS; [TSPLIT,512) in d_ws (proven 524KB)
#define NEGV (-10000.0f)

// ---------- pre-pass: in-place row-wise log_softmax (R6-proven, absmax 0) ----------
__global__ __launch_bounds__(256) void lsm_kernel(float* __restrict__ u) {
    const int g0 = (blockIdx.x * 256 + threadIdx.x) >> 5;   // half-wave id, 0..16383
    const int l  = threadIdx.x & 31;
    const int NG = 2048 * 8;                                // groups per pass
    float4* base = (float4*)u;                              // row r: base[r*32 + l]
    int row = g0;
    float4 v = base[(size_t)row * 32 + l];
#pragma unroll
    for (int it = 0; it < 8; ++it) {                        // 8*16384 = 131072 rows
        const int nrow = row + NG;
        float4 vn = make_float4(0.f, 0.f, 0.f, 0.f);
        if (it < 7) vn = base[(size_t)nrow * 32 + l];       // prefetch next row
        float m = fmaxf(fmaxf(v.x, v.y), fmaxf(v.z, v.w));
#pragma unroll
        for (int off = 16; off; off >>= 1) m = fmaxf(m, __shfl_xor(m, off, 64));
        float s = expf(v.x - m) + expf(v.y - m) + expf(v.z - m) + expf(v.w - m);
#pragma unroll
        for (int off = 16; off; off >>= 1) s += __shfl_xor(s, off, 64);
        float ls = logf(s);
        base[(size_t)row * 32 + l] =
            make_float4((v.x - m) - ls, (v.y - m) - ls, (v.z - m) - ls, (v.w - m) - ls);
        v = vn; row = nrow;
    }
}

// ---------- serial Viterbi: 128 threads = 2 waves, 1 thread per cur ----------
// No shuffles, no combine: each thread scans all 128 prevs ascending (exact
// jnp.argmax first-max semantics). One narrow 2-wave barrier per step.
__global__ __launch_bounds__(128) void viterbi_kernel(
    const float* __restrict__ probs,     // [B,T,N] log-softmaxed
    const float* __restrict__ trans,     // [1,N,N] trans0[cur][prev]
    const int*   __restrict__ lengths_raw,
    float* __restrict__ out,             // [B*T] preds then [B] scores
    unsigned char* __restrict__ ws)
{
    __shared__ unsigned char bps[(TSPLIT - 1) * NN];   // 63360 B
    __shared__ __align__(16) float alpha[2][NN];       // double-buffered; reads are broadcasts
    __shared__ float fin_v[2];
    __shared__ int   fin_i[2];

    const int tid  = threadIdx.x;        // 0..127
    const int b    = blockIdx.x;
    const int wave = tid >> 6;
    const int lane = tid & 63;
    const int cur  = tid;                // tag owned by this thread

    int len;
    {
        int probe = lengths_raw[1];      // ==0 iff int64 (lengths >= 256 > 0)
        len = (probe == 0) ? lengths_raw[2 * b] : lengths_raw[b];
    }

    // full trans row in registers: tr[j] = trans0[cur][j]
    float tr[128];
    {
        const float4* t4 = (const float4*)(trans + cur * NN);
#pragma unroll
        for (int i = 0; i < 32; ++i) {
            float4 v = t4[i];
            tr[4*i+0] = v.x; tr[4*i+1] = v.y; tr[4*i+2] = v.z; tr[4*i+3] = v.w;
        }
    }

    alpha[0][tid] = (tid == GO_IDX) ? 0.0f : NEGV;

    const float* pb = probs + (size_t)b * TT * NN;
    unsigned char* wst = ws + (size_t)b * ((TT - TSPLIT) * NN);

    // 8-deep register window of p[t][cur] (all threads, coalesced)
    float P[8], Nx[8];
#pragma unroll
    for (int k = 0; k < 8; ++k) P[k] = pb[k * NN + cur];
    __syncthreads();

    const int nG = (len + 7) >> 3;
    for (int g = 0; g < nG; ++g) {
        const int tb = g * 8;
#pragma unroll
        for (int k = 0; k < 8; ++k) {
            int tt = tb + 8 + k; if (tt > TT - 1) tt = TT - 1;
            Nx[k] = pb[tt * NN + cur];
        }
#pragma unroll
        for (int k = 0; k < 8; ++k) {
            const int t = tb + k;
            if (t < len) {                         // uniform per block
                const float4* ra4 = (const float4*)alpha[t & 1];
                float*        wa  = alpha[(t & 1) ^ 1];
                // 8 independent chains x 16 prevs (ILP), ascending scan, strict >
                float bv[8]; int bi[8];
#pragma unroll
                for (int c = 0; c < 8; ++c) {
                    float4 a0 = ra4[4*c+0], a1 = ra4[4*c+1], a2 = ra4[4*c+2], a3 = ra4[4*c+3];
                    const int base = c * 16;
                    bv[c] = a0.x + tr[base + 0]; bi[c] = base + 0;
                    float x;
                    x = a0.y + tr[base + 1];  if (x > bv[c]) { bv[c] = x; bi[c] = base + 1; }
                    x = a0.z + tr[base + 2];  if (x > bv[c]) { bv[c] = x; bi[c] = base + 2; }
                    x = a0.w + tr[base + 3];  if (x > bv[c]) { bv[c] = x; bi[c] = base + 3; }
                    x = a1.x + tr[base + 4];  if (x > bv[c]) { bv[c] = x; bi[c] = base + 4; }
                    x = a1.y + tr[base + 5];  if (x > bv[c]) { bv[c] = x; bi[c] = base + 5; }
                    x = a1.z + tr[base + 6];  if (x > bv[c]) { bv[c] = x; bi[c] = base + 6; }
                    x = a1.w + tr[base + 7];  if (x > bv[c]) { bv[c] = x; bi[c] = base + 7; }
                    x = a2.x + tr[base + 8];  if (x > bv[c]) { bv[c] = x; bi[c] = base + 8; }
                    x = a2.y + tr[base + 9];  if (x > bv[c]) { bv[c] = x; bi[c] = base + 9; }
                    x = a2.z + tr[base + 10]; if (x > bv[c]) { bv[c] = x; bi[c] = base + 10; }
                    x = a2.w + tr[base + 11]; if (x > bv[c]) { bv[c] = x; bi[c] = base + 11; }
                    x = a3.x + tr[base + 12]; if (x > bv[c]) { bv[c] = x; bi[c] = base + 12; }
                    x = a3.y + tr[base + 13]; if (x > bv[c]) { bv[c] = x; bi[c] = base + 13; }
                    x = a3.z + tr[base + 14]; if (x > bv[c]) { bv[c] = x; bi[c] = base + 14; }
                    x = a3.w + tr[base + 15]; if (x > bv[c]) { bv[c] = x; bi[c] = base + 15; }
                }
                float best = bv[0]; int bp = bi[0];
#pragma unroll
                for (int c = 1; c < 8; ++c) { if (bv[c] > best) { best = bv[c]; bp = bi[c]; } }

                wa[cur] = best + P[k];
                if (t >= 1) {
                    if (t < TSPLIT) bps[(t - 1) * NN + cur] = (unsigned char)bp;
                    else            wst[(t - TSPLIT) * NN + cur] = (unsigned char)bp;
                }
                __syncthreads();
            }
        }
#pragma unroll
        for (int k = 0; k < 8; ++k) P[k] = Nx[k];
    }

    __threadfence();   // tail bp global writes visible to thread 0

    // terminal: argmax(alpha + trans0[EOS][:]), first-max tie-break
    {
        float v = alpha[len & 1][tid] + trans[EOS_IDX * NN + tid];
        int idx = tid;
#pragma unroll
        for (int off = 32; off; off >>= 1) {
            float ov = __shfl_xor(v, off, 64);
            int   oi = __shfl_xor(idx, off, 64);
            if (ov > v || (ov == v && oi < idx)) { v = ov; idx = oi; }
        }
        if (lane == 0) { fin_v[wave] = v; fin_i[wave] = idx; }
    }
    __syncthreads();

    for (int t = len + tid; t < TT; t += 128) out[(size_t)b * TT + t] = 0.0f;

    if (tid == 0) {
        float v0 = fin_v[0], v1 = fin_v[1];
        int   i0 = fin_i[0], i1 = fin_i[1];
        float sc; int tag;
        if (v1 > v0) { sc = v1; tag = i1; }
        else         { sc = v0; tag = i0; }
        out[(size_t)BB * TT + b] = sc;

        for (int t = len - 1; t >= 0; --t) {
            out[(size_t)b * TT + t] = (float)tag;
            if (t >= 1) {
                int nb;
                if (t < TSPLIT) nb = bps[(t - 1) * NN + tag];
                else            nb = ((volatile const unsigned char*)wst)[(t - TSPLIT) * NN + tag];
                tag = nb;
            }
        }
    }
}

extern "C" void kernel_launch(void* const* d_in, const int* in_sizes, int n_in,
                              void* d_out, int out_size, void* d_ws, size_t ws_size,
                              hipStream_t stream) {
    float*       unaries = (float*)d_in[0];          // transformed in-place to log-softmax
    const float* trans   = (const float*)d_in[1];
    const int*   lengths = (const int*)d_in[2];
    float* out = (float*)d_out;
    unsigned char* ws = (unsigned char*)d_ws;

    hipLaunchKernelGGL(lsm_kernel, dim3(2048), dim3(256), 0, stream, unaries);
    hipLaunchKernelGGL(viterbi_kernel, dim3(BB), dim3(128), 0, stream,
                       unaries, trans, lengths, out, ws);
}

// Round 9
// 508.616 us; speedup vs baseline: 2.2912x; 2.2912x over previous
//
#include <hip/hip_runtime.h>

#define BB 256
#define TT 512
#define NN 128
#define GO_IDX 1
#define EOS_IDX 2
#define TSPLIT 496            // bp rows t in [1,TSPLIT) in LDS; [TSPLIT,512) in d_ws (proven 524KB)
#define NEGV (-10000.0f)
// padded alpha slot: x + (x>>5)*4  -> quarter bases at 0,36,72,108 (banks 0,4,8,12; 16B aligned)
#define ASLOT(x) ((x) + (((x) >> 5) << 2))

// ---------- DPP quad_perm helpers: cross-lane within groups of 4, VALU-speed ----------
__device__ __forceinline__ float dpp_xor1_f(float x) {      // quad_perm [1,0,3,2]
    return __int_as_float(__builtin_amdgcn_update_dpp(0, __float_as_int(x), 0xB1, 0xF, 0xF, true));
}
__device__ __forceinline__ float dpp_xor2_f(float x) {      // quad_perm [2,3,0,1]
    return __int_as_float(__builtin_amdgcn_update_dpp(0, __float_as_int(x), 0x4E, 0xF, 0xF, true));
}
__device__ __forceinline__ int dpp_xor1_i(int x) {
    return __builtin_amdgcn_update_dpp(0, x, 0xB1, 0xF, 0xF, true);
}
__device__ __forceinline__ int dpp_xor2_i(int x) {
    return __builtin_amdgcn_update_dpp(0, x, 0x4E, 0xF, 0xF, true);
}

// ---------- pre-pass: in-place row-wise log_softmax (R6-proven, absmax 0) ----------
__global__ __launch_bounds__(256) void lsm_kernel(float* __restrict__ u) {
    const int g0 = (blockIdx.x * 256 + threadIdx.x) >> 5;   // half-wave id, 0..16383
    const int l  = threadIdx.x & 31;
    const int NG = 2048 * 8;                                // groups per pass
    float4* base = (float4*)u;                              // row r: base[r*32 + l]
    int row = g0;
    float4 v = base[(size_t)row * 32 + l];
#pragma unroll
    for (int it = 0; it < 8; ++it) {                        // 8*16384 = 131072 rows
        const int nrow = row + NG;
        float4 vn = make_float4(0.f, 0.f, 0.f, 0.f);
        if (it < 7) vn = base[(size_t)nrow * 32 + l];       // prefetch next row
        float m = fmaxf(fmaxf(v.x, v.y), fmaxf(v.z, v.w));
#pragma unroll
        for (int off = 16; off; off >>= 1) m = fmaxf(m, __shfl_xor(m, off, 64));
        float s = expf(v.x - m) + expf(v.y - m) + expf(v.z - m) + expf(v.w - m);
#pragma unroll
        for (int off = 16; off; off >>= 1) s += __shfl_xor(s, off, 64);
        float ls = logf(s);
        base[(size_t)row * 32 + l] =
            make_float4((v.x - m) - ls, (v.y - m) - ls, (v.z - m) - ls, (v.w - m) - ls);
        v = vn; row = nrow;
    }
}

// ---------- serial Viterbi: 512 threads, 4 threads per cur, DPP quad combine ----------
__global__ __launch_bounds__(512) void viterbi_kernel(
    const float* __restrict__ probs,     // [B,T,N] log-softmaxed
    const float* __restrict__ trans,     // [1,N,N] trans0[cur][prev]
    const int*   __restrict__ lengths_raw,
    float* __restrict__ out,             // [B*T] preds then [B] scores
    unsigned char* __restrict__ ws)
{
    __shared__ unsigned char bps[(TSPLIT - 1) * NN];   // 63360 B
    __shared__ __align__(16) float alpha[2][144];      // padded, double-buffered
    __shared__ float fin_v[2];
    __shared__ int   fin_i[2];

    const int tid  = threadIdx.x;
    const int b    = blockIdx.x;
    const int wave = tid >> 6;
    const int lane = tid & 63;
    const int q    = tid & 3;              // prev-quarter owned by this lane
    const int cur  = tid >> 2;             // tag owned by this quad (0..127)

    int len;
    {
        int probe = lengths_raw[1];        // ==0 iff int64 (lengths >= 256 > 0)
        len = (probe == 0) ? lengths_raw[2 * b] : lengths_raw[b];
    }

    // trans chunk in registers: trans0[cur][q*32 + j], j in [0,32)
    float tr[32];
    {
        const float4* t4 = (const float4*)(trans + cur * NN + q * 32);
#pragma unroll
        for (int i = 0; i < 8; ++i) {
            float4 v = t4[i];
            tr[4*i+0] = v.x; tr[4*i+1] = v.y; tr[4*i+2] = v.z; tr[4*i+3] = v.w;
        }
    }

    if (tid < NN) alpha[0][ASLOT(tid)] = (tid == GO_IDX) ? 0.0f : NEGV;

    const float* pb = probs + (size_t)b * TT * NN;
    unsigned char* wst = ws + (size_t)b * ((TT - TSPLIT) * NN);

    // 8-deep register window of p[t][cur] (q==0 lanes only)
    float P[8], Nx[8];
    if (q == 0) {
#pragma unroll
        for (int k = 0; k < 8; ++k) P[k] = pb[k * NN + cur];
    }
    __syncthreads();

    const int nG = (len + 7) >> 3;
    for (int g = 0; g < nG; ++g) {
        const int tb = g * 8;
        if (q == 0) {
#pragma unroll
            for (int k = 0; k < 8; ++k) {
                int tt = tb + 8 + k; if (tt > TT - 1) tt = TT - 1;
                Nx[k] = pb[tt * NN + cur];
            }
        }
#pragma unroll
        for (int k = 0; k < 8; ++k) {
            const int t = tb + k;
            if (t < len) {                         // uniform per block
                const float* ra = alpha[t & 1];
                float*       wa = alpha[(t & 1) ^ 1];
                const float4* a4 = (const float4*)(ra + q * 36);  // banks 0/4/8/12 per quarter
                float bv[4]; int bi[4];
#pragma unroll
                for (int c = 0; c < 4; ++c) {      // 4 chains x 8 prevs, ascending strict >
                    float4 a0 = a4[c * 2], a1 = a4[c * 2 + 1];
                    const int base = c * 8;
                    bv[c] = a0.x + tr[base + 0]; bi[c] = base + 0;
                    float x;
                    x = a0.y + tr[base + 1]; if (x > bv[c]) { bv[c] = x; bi[c] = base + 1; }
                    x = a0.z + tr[base + 2]; if (x > bv[c]) { bv[c] = x; bi[c] = base + 2; }
                    x = a0.w + tr[base + 3]; if (x > bv[c]) { bv[c] = x; bi[c] = base + 3; }
                    x = a1.x + tr[base + 4]; if (x > bv[c]) { bv[c] = x; bi[c] = base + 4; }
                    x = a1.y + tr[base + 5]; if (x > bv[c]) { bv[c] = x; bi[c] = base + 5; }
                    x = a1.z + tr[base + 6]; if (x > bv[c]) { bv[c] = x; bi[c] = base + 6; }
                    x = a1.w + tr[base + 7]; if (x > bv[c]) { bv[c] = x; bi[c] = base + 7; }
                }
                float best = bv[0]; int bp = bi[0];
#pragma unroll
                for (int c = 1; c < 4; ++c) { if (bv[c] > best) { best = bv[c]; bp = bi[c]; } }
                bp += q * 32;                      // absolute prev index

                // DPP quad combine (value + index). Tie-break identical to R4:
                // even q: strict > keeps own (lower prev range); odd q: >= takes lower partner.
                float v1 = dpp_xor1_f(best); int b1 = dpp_xor1_i(bp);
                bool  t1 = (q & 1) ? (v1 >= best) : (v1 > best);
                float m1 = t1 ? v1 : best;   int p1 = t1 ? b1 : bp;
                float v2 = dpp_xor2_f(m1);   int b2 = dpp_xor2_i(p1);
                bool  t2 = (q & 2) ? (v2 >= m1) : (v2 > m1);
                float M  = t2 ? v2 : m1;     int BP = t2 ? b2 : p1;

                if (q == 0) {
                    wa[ASLOT(cur)] = M + P[k];
                    if (t >= 1) {
                        if (t < TSPLIT) bps[(t - 1) * NN + cur] = (unsigned char)BP;
                        else            wst[(t - TSPLIT) * NN + cur] = (unsigned char)BP;
                    }
                }
                __syncthreads();
            }
        }
#pragma unroll
        for (int k = 0; k < 8; ++k) P[k] = Nx[k];
    }

    __threadfence();   // tail bp global writes visible to thread 0

    // terminal: argmax(alpha + trans0[EOS][:]), first-max tie-break
    if (tid < NN) {
        float v = alpha[len & 1][ASLOT(tid)] + trans[EOS_IDX * NN + tid];
        int idx = tid;
#pragma unroll
        for (int off = 32; off; off >>= 1) {
            float ov = __shfl_xor(v, off, 64);
            int   oi = __shfl_xor(idx, off, 64);
            if (ov > v || (ov == v && oi < idx)) { v = ov; idx = oi; }
        }
        if (lane == 0) { fin_v[wave] = v; fin_i[wave] = idx; }
    }
    __syncthreads();

    for (int t = len + tid; t < TT; t += 512) out[(size_t)b * TT + t] = 0.0f;

    if (tid == 0) {
        float v0 = fin_v[0], v1 = fin_v[1];
        int   i0 = fin_i[0], i1 = fin_i[1];
        float sc; int tag;
        if (v1 > v0) { sc = v1; tag = i1; }
        else         { sc = v0; tag = i0; }
        out[(size_t)BB * TT + b] = sc;

        for (int t = len - 1; t >= 0; --t) {
            out[(size_t)b * TT + t] = (float)tag;
            if (t >= 1) {
                int nb;
                if (t < TSPLIT) nb = bps[(t - 1) * NN + tag];
                else            nb = ((volatile const unsigned char*)wst)[(t - TSPLIT) * NN + tag];
                tag = nb;
            }
        }
    }
}

extern "C" void kernel_launch(void* const* d_in, const int* in_sizes, int n_in,
                              void* d_out, int out_size, void* d_ws, size_t ws_size,
                              hipStream_t stream) {
    float*       unaries = (float*)d_in[0];          // transformed in-place to log-softmax
    const float* trans   = (const float*)d_in[1];
    const int*   lengths = (const int*)d_in[2];
    float* out = (float*)d_out;
    unsigned char* ws = (unsigned char*)d_ws;

    hipLaunchKernelGGL(lsm_kernel, dim3(2048), dim3(256), 0, stream, unaries);
    hipLaunchKernelGGL(viterbi_kernel, dim3(BB), dim3(512), 0, stream,
                       unaries, trans, lengths, out, ws);
}

// Round 10
// 507.067 us; speedup vs baseline: 2.2983x; 1.0031x over previous
//
#include <hip/hip_runtime.h>

#define BB 256
#define TT 512
#define NN 128
#define GO_IDX 1
#define EOS_IDX 2
#define TSPLIT 496            // bp rows t in [1,TSPLIT) in LDS; [TSPLIT,512) in d_ws (proven 524KB)
#define NEGV (-10000.0f)
// padded alpha slot: x + (x>>5)*4  -> quarter bases at 0,36,72,108 (banks 0,4,8,12; 16B aligned)
#define ASLOT(x) ((x) + (((x) >> 5) << 2))

// step barrier: drain LDS only (alpha/bps), leave global prefetch loads in flight.
// (HIP __syncthreads would add vmcnt(0) — re-exposing HBM latency every step.)
#define STEP_BARRIER() asm volatile("s_waitcnt lgkmcnt(0)\n\ts_barrier" ::: "memory")

// ---------- DPP quad_perm helpers: cross-lane within groups of 4, VALU-speed ----------
__device__ __forceinline__ float dpp_xor1_f(float x) {      // quad_perm [1,0,3,2]
    return __int_as_float(__builtin_amdgcn_update_dpp(0, __float_as_int(x), 0xB1, 0xF, 0xF, true));
}
__device__ __forceinline__ float dpp_xor2_f(float x) {      // quad_perm [2,3,0,1]
    return __int_as_float(__builtin_amdgcn_update_dpp(0, __float_as_int(x), 0x4E, 0xF, 0xF, true));
}
__device__ __forceinline__ int dpp_xor1_i(int x) {
    return __builtin_amdgcn_update_dpp(0, x, 0xB1, 0xF, 0xF, true);
}
__device__ __forceinline__ int dpp_xor2_i(int x) {
    return __builtin_amdgcn_update_dpp(0, x, 0x4E, 0xF, 0xF, true);
}

// ---------- pre-pass: in-place row-wise log_softmax, skipping rows >= len ----------
// per-row math identical to the R6-proven kernel (float4 + 5-level butterfly, absmax-0 class)
__global__ __launch_bounds__(256) void lsm_kernel(float* __restrict__ u,
                                                  const int* __restrict__ lengths_raw) {
    const int g0 = (blockIdx.x * 256 + threadIdx.x) >> 5;   // half-wave id, 0..16383
    const int l  = threadIdx.x & 31;
    const int b  = g0 >> 6;                                 // 64 half-waves per batch
    const int j  = g0 & 63;                                 // row stripe within batch
    int len;
    {
        int probe = lengths_raw[1];                         // ==0 iff int64 (lengths >= 256 > 0)
        len = (probe == 0) ? lengths_raw[2 * b] : lengths_raw[b];
    }
    float4* base = (float4*)(u + (size_t)b * TT * NN);      // row r: base[r*32 + l]
    int row = j;                                            // j < 64 <= len always
    float4 v = base[row * 32 + l];
    for (;;) {
        const int nrow = row + 64;
        const bool more = (nrow < len);
        float4 vn;
        if (more) vn = base[nrow * 32 + l];                 // prefetch next row
        float m = fmaxf(fmaxf(v.x, v.y), fmaxf(v.z, v.w));
#pragma unroll
        for (int off = 16; off; off >>= 1) m = fmaxf(m, __shfl_xor(m, off, 64));
        float s = expf(v.x - m) + expf(v.y - m) + expf(v.z - m) + expf(v.w - m);
#pragma unroll
        for (int off = 16; off; off >>= 1) s += __shfl_xor(s, off, 64);
        float ls = logf(s);
        base[row * 32 + l] =
            make_float4((v.x - m) - ls, (v.y - m) - ls, (v.z - m) - ls, (v.w - m) - ls);
        if (!more) break;
        v = vn; row = nrow;
    }
}

// ---------- serial Viterbi: 512 threads, 4 threads per cur, DPP quad combine ----------
__global__ __launch_bounds__(512) void viterbi_kernel(
    const float* __restrict__ probs,     // [B,T,N] log-softmaxed
    const float* __restrict__ trans,     // [1,N,N] trans0[cur][prev]
    const int*   __restrict__ lengths_raw,
    float* __restrict__ out,             // [B*T] preds then [B] scores
    unsigned char* __restrict__ ws)
{
    __shared__ unsigned char bps[(TSPLIT - 1) * NN];   // 63360 B
    __shared__ __align__(16) float alpha[2][144];      // padded, double-buffered
    __shared__ float fin_v[2];
    __shared__ int   fin_i[2];

    const int tid  = threadIdx.x;
    const int b    = blockIdx.x;
    const int wave = tid >> 6;
    const int lane = tid & 63;
    const int q    = tid & 3;              // prev-quarter owned by this lane
    const int cur  = tid >> 2;             // tag owned by this quad (0..127)

    int len;
    {
        int probe = lengths_raw[1];        // ==0 iff int64 (lengths >= 256 > 0)
        len = (probe == 0) ? lengths_raw[2 * b] : lengths_raw[b];
    }

    // trans chunk in registers: trans0[cur][q*32 + j], j in [0,32)
    float tr[32];
    {
        const float4* t4 = (const float4*)(trans + cur * NN + q * 32);
#pragma unroll
        for (int i = 0; i < 8; ++i) {
            float4 v = t4[i];
            tr[4*i+0] = v.x; tr[4*i+1] = v.y; tr[4*i+2] = v.z; tr[4*i+3] = v.w;
        }
    }

    if (tid < NN) alpha[0][ASLOT(tid)] = (tid == GO_IDX) ? 0.0f : NEGV;

    const float* pb = probs + (size_t)b * TT * NN;
    unsigned char* wst = ws + (size_t)b * ((TT - TSPLIT) * NN);

    // 8-deep register window of p[t][cur] (q==0 lanes only)
    float P[8], Nx[8];
    if (q == 0) {
#pragma unroll
        for (int k = 0; k < 8; ++k) P[k] = pb[k * NN + cur];
    }
    __syncthreads();

    const int nG = (len + 7) >> 3;
    for (int g = 0; g < nG; ++g) {
        const int tb = g * 8;
        if (q == 0) {
#pragma unroll
            for (int k = 0; k < 8; ++k) {
                int tt = tb + 8 + k; if (tt > TT - 1) tt = TT - 1;
                Nx[k] = pb[tt * NN + cur];
            }
        }
#pragma unroll
        for (int k = 0; k < 8; ++k) {
            const int t = tb + k;
            if (t < len) {                         // uniform per block
                const float* ra = alpha[t & 1];
                float*       wa = alpha[(t & 1) ^ 1];
                const float4* a4 = (const float4*)(ra + q * 36);  // banks 0/4/8/12 per quarter
                float bv[4]; int bi[4];
#pragma unroll
                for (int c = 0; c < 4; ++c) {      // 4 chains x 8 prevs, ascending strict >
                    float4 a0 = a4[c * 2], a1 = a4[c * 2 + 1];
                    const int base = c * 8;
                    bv[c] = a0.x + tr[base + 0]; bi[c] = base + 0;
                    float x;
                    x = a0.y + tr[base + 1]; if (x > bv[c]) { bv[c] = x; bi[c] = base + 1; }
                    x = a0.z + tr[base + 2]; if (x > bv[c]) { bv[c] = x; bi[c] = base + 2; }
                    x = a0.w + tr[base + 3]; if (x > bv[c]) { bv[c] = x; bi[c] = base + 3; }
                    x = a1.x + tr[base + 4]; if (x > bv[c]) { bv[c] = x; bi[c] = base + 4; }
                    x = a1.y + tr[base + 5]; if (x > bv[c]) { bv[c] = x; bi[c] = base + 5; }
                    x = a1.z + tr[base + 6]; if (x > bv[c]) { bv[c] = x; bi[c] = base + 6; }
                    x = a1.w + tr[base + 7]; if (x > bv[c]) { bv[c] = x; bi[c] = base + 7; }
                }
                float best = bv[0]; int bp = bi[0];
#pragma unroll
                for (int c = 1; c < 4; ++c) { if (bv[c] > best) { best = bv[c]; bp = bi[c]; } }
                bp += q * 32;                      // absolute prev index

                // DPP quad combine (value + index). Tie-break identical to R4:
                // even q: strict > keeps own (lower prev range); odd q: >= takes lower partner.
                float v1 = dpp_xor1_f(best); int b1 = dpp_xor1_i(bp);
                bool  t1 = (q & 1) ? (v1 >= best) : (v1 > best);
                float m1 = t1 ? v1 : best;   int p1 = t1 ? b1 : bp;
                float v2 = dpp_xor2_f(m1);   int b2 = dpp_xor2_i(p1);
                bool  t2 = (q & 2) ? (v2 >= m1) : (v2 > m1);
                float M  = t2 ? v2 : m1;     int BP = t2 ? b2 : p1;

                if (q == 0) {
                    wa[ASLOT(cur)] = M + P[k];
                    if (t >= 1) {
                        if (t < TSPLIT) bps[(t - 1) * NN + cur] = (unsigned char)BP;
                        else            wst[(t - TSPLIT) * NN + cur] = (unsigned char)BP;
                    }
                }
                STEP_BARRIER();    // lgkmcnt(0) only — global prefetch stays in flight
            }
        }
#pragma unroll
        for (int k = 0; k < 8; ++k) P[k] = Nx[k];
    }

    __threadfence();   // tail bp global writes visible to thread 0

    // terminal: argmax(alpha + trans0[EOS][:]), first-max tie-break
    if (tid < NN) {
        float v = alpha[len & 1][ASLOT(tid)] + trans[EOS_IDX * NN + tid];
        int idx = tid;
#pragma unroll
        for (int off = 32; off; off >>= 1) {
            float ov = __shfl_xor(v, off, 64);
            int   oi = __shfl_xor(idx, off, 64);
            if (ov > v || (ov == v && oi < idx)) { v = ov; idx = oi; }
        }
        if (lane == 0) { fin_v[wave] = v; fin_i[wave] = idx; }
    }
    __syncthreads();   // full sync: drains everything before backtrace reads

    for (int t = len + tid; t < TT; t += 512) out[(size_t)b * TT + t] = 0.0f;

    if (tid == 0) {
        float v0 = fin_v[0], v1 = fin_v[1];
        int   i0 = fin_i[0], i1 = fin_i[1];
        float sc; int tag;
        if (v1 > v0) { sc = v1; tag = i1; }
        else         { sc = v0; tag = i0; }
        out[(size_t)BB * TT + b] = sc;

        for (int t = len - 1; t >= 0; --t) {
            out[(size_t)b * TT + t] = (float)tag;
            if (t >= 1) {
                int nb;
                if (t < TSPLIT) nb = bps[(t - 1) * NN + tag];
                else            nb = ((volatile const unsigned char*)wst)[(t - TSPLIT) * NN + tag];
                tag = nb;
            }
        }
    }
}

extern "C" void kernel_launch(void* const* d_in, const int* in_sizes, int n_in,
                              void* d_out, int out_size, void* d_ws, size_t ws_size,
                              hipStream_t stream) {
    float*       unaries = (float*)d_in[0];          // transformed in-place to log-softmax
    const float* trans   = (const float*)d_in[1];
    const int*   lengths = (const int*)d_in[2];
    float* out = (float*)d_out;
    unsigned char* ws = (unsigned char*)d_ws;

    hipLaunchKernelGGL(lsm_kernel, dim3(2048), dim3(256), 0, stream, unaries, lengths);
    hipLaunchKernelGGL(viterbi_kernel, dim3(BB), dim3(512), 0, stream,
                       unaries, trans, lengths, out, ws);
}